// Round 8
// baseline (521.445 us; speedup 1.0000x reference)
//
#include <hip/hip_runtime.h>
#include <hip/hip_bf16.h>

typedef unsigned short ushortT;
typedef __bf16 bf16x8 __attribute__((ext_vector_type(8)));
typedef float f32x4 __attribute__((ext_vector_type(4)));

#define OUT_SCALE 0.001f

// fast GELU: v * sigmoid(1.5957691*(v + 0.044715 v^3)); |err vs exact| <~1e-3
__device__ __forceinline__ float gelu_fast(float v) {
    const float u = v * fmaf(0.044715f * v, v, 1.0f);
    const float e = __expf(-1.5957691216057308f * u);
    return v * __builtin_amdgcn_rcpf(1.0f + e);
}
__device__ __forceinline__ ushortT f2bf(float f) {
    __hip_bfloat16 h = __float2bfloat16(f);
    return *reinterpret_cast<ushortT*>(&h);
}

// ---------------------------------------------------------------------------
// K2: z path, split per 16 channels. grid (64,4), 256 thr, LDS 16.6 KB.
// gelu(z + dwconv3x3(z) + b) -> bf16 ZB[b][v][u][c64]
// ---------------------------------------------------------------------------
__global__ __launch_bounds__(256) void k_gelu_z(
    const float* __restrict__ z, const float* __restrict__ wz,
    const float* __restrict__ bz, ushortT* __restrict__ zbuf)
{
    const int b  = blockIdx.x;
    const int cg = blockIdx.y;        // channel group of 16
    const int tid = threadIdx.x;

    __shared__ float zs[16 * 260];    // 16 ch x 256 (+4 pad)

    for (int i = tid; i < 1024; i += 256) {
        const int c_l = i >> 6, pos = i & 63;
        *(float4*)(zs + c_l * 260 + pos * 4) =
            *(const float4*)(z + ((size_t)(b * 64 + cg * 16 + c_l)) * 256 + pos * 4);
    }
    __syncthreads();

    const int c_l = tid & 15;         // local channel
    const int v   = tid >> 4;         // search col (0..15)
    const int c   = cg * 16 + c_l;

    float w[9];
    #pragma unroll
    for (int i = 0; i < 9; ++i) w[i] = wz[c * 9 + i];
    const float bias = bz[c];
    const float* zc = zs + c_l * 260;
    ushortT* zo = zbuf + (size_t)b * 16384 + c;

    #pragma unroll
    for (int u = 0; u < 16; ++u) {
        float acc = bias;
        #pragma unroll
        for (int dr = 0; dr < 3; ++dr) {
            const int uu = u + dr - 1;
            if (uu < 0 || uu >= 16) continue;
            #pragma unroll
            for (int dc = 0; dc < 3; ++dc) {
                const int vv = v + dc - 1;
                if (vv < 0 || vv >= 16) continue;
                acc += zc[uu * 16 + vv] * w[dr * 3 + dc];
            }
        }
        const float y = acc + zc[u * 16 + v];
        zo[(v * 16 + u) * 64] = f2bf(gelu_fast(y));
    }
}

// ---------------------------------------------------------------------------
// K-fused v3: rolling 6-row software pipeline per block. grid 1024, 512 thr.
// Per iteration: issue ONE new x-row's 5 float4 loads (rolling 3-row register
// window) -> sched_barrier -> Phase B (MFMA row t from rowbuf[t&1]) -> finish
// loads + A-compute row t+1 into rowbuf[(t+1)&1] -> barrier. Load latency is
// hidden under Phase B BY DATAFLOW (consumed only after B), x-load volume /4.
// ---------------------------------------------------------------------------
__global__ __launch_bounds__(512, 4) void k_fused(
    const float* __restrict__ x, const float* __restrict__ wx,
    const float* __restrict__ bx, const ushortT* __restrict__ zbuf,
    float* __restrict__ part)
{
    // bijective XCD swizzle: 1024 = 8 * 128; same-b blocks land on same XCD
    const int lin = blockIdx.x;
    const int sw  = ((lin & 7) << 7) + (lin >> 3);
    const int b   = sw >> 4;          // 64 batches
    const int r0  = (sw & 15) * 6;    // 16 groups of 6 rows
    const int tid = threadIdx.x;

    __shared__ ushortT rowbuf[2][8192];   // [buf][g2][T128][c32 swizzled]

    // zero-pad T in [0,8) and [104,128) for both bufs x g: 512 uint4, once
    {
        const int bu = tid >> 8, g = (tid >> 7) & 1, t = tid & 127;
        const int off = (t < 32) ? t * 8 : 3328 + (t - 32) * 8;
        *(uint4*)(&rowbuf[bu][g * 4096 + off]) = make_uint4(0, 0, 0, 0);
    }

    const int c = tid >> 3, colg = tid & 7, j0 = colg * 12;
    const int g_ = c >> 5, cl = c & 31, chunk = cl >> 3, pos = cl & 7;
    const int wave = tid >> 6, lane = tid & 63;
    const int n = lane & 15, q = lane >> 4, j0a = wave * 16;
    const bool ledge = (colg == 0), redge = (colg == 7);

    float w[9];
    #pragma unroll
    for (int i = 0; i < 9; ++i) w[i] = wx[c * 9 + i];
    const float bias = bx[c];
    const float* xb = x + (size_t)(b * 64 + c) * 9216;
    const ushortT* zb = zbuf + (size_t)b * 16384;

    // rolling register window: W[s][20] holds 3 consecutive input rows
    float W[3][20];

    // prologue: rows r0-1, r0, r0+1 -> W[0..2]
    #pragma unroll
    for (int s = 0; s < 3; ++s) {
        const int rr  = r0 - 1 + s;
        const int rcl = (rr < 0) ? 0 : rr;   // only s=0 can underflow
        const bool rok = (rr >= 0);
        const float* xr = xb + rcl * 96;
        #pragma unroll
        for (int m = 0; m < 5; ++m) {
            const int cs  = j0 - 4 + 4 * m;
            const int csc = (cs < 0) ? 0 : (cs > 92 ? 92 : cs);
            const float4 v = *(const float4*)(xr + csc);
            const bool ok = rok && !(m == 0 && ledge) && !(m == 4 && redge);
            W[s][4*m+0] = ok ? v.x : 0.f;
            W[s][4*m+1] = ok ? v.y : 0.f;
            W[s][4*m+2] = ok ? v.z : 0.f;
            W[s][4*m+3] = ok ? v.w : 0.f;
        }
    }

    // A-compute row r0 -> rowbuf[0]
    {
        ushortT* rbw = &rowbuf[0][0] + g_ * 4096;
        #pragma unroll
        for (int jj = 0; jj < 12; ++jj) {
            const float a = bias
              + W[0][jj+3]*w[0] + W[0][jj+4]*w[1] + W[0][jj+5]*w[2]
              + W[1][jj+3]*w[3] + W[1][jj+4]*w[4] + W[1][jj+5]*w[5] + W[1][jj+4]
              + W[2][jj+3]*w[6] + W[2][jj+4]*w[7] + W[2][jj+5]*w[8];
            const int T = j0 + jj + 8;
            rbw[T*32 + ((chunk ^ ((T>>1)&3)) << 3) + pos] = f2bf(gelu_fast(a));
        }
    }
    __syncthreads();

    #pragma unroll
    for (int it = 0; it < 6; ++it) {
        // 1) issue next input row's loads (row r0+it+2) -- raw, no selects
        float4 raw[5];
        bool rok = false;
        if (it < 5) {
            const int rr  = r0 + it + 2;
            const int rcl = (rr > 95) ? 95 : rr;
            rok = (rr <= 95);
            const float* xr = xb + rcl * 96;
            #pragma unroll
            for (int m = 0; m < 5; ++m) {
                const int cs  = j0 - 4 + 4 * m;
                const int csc = (cs < 0) ? 0 : (cs > 92 ? 92 : cs);
                raw[m] = *(const float4*)(xr + csc);
            }
        }
        __builtin_amdgcn_sched_barrier(0);   // pin load issue above Phase B

        // 2) Phase B: MFMA row r0+it from rowbuf[it&1]
        if (wave < 7) {
            const ushortT* rb = &rowbuf[it & 1][0];
            f32x4 acc = {0.f, 0.f, 0.f, 0.f};
            #pragma unroll
            for (int g = 0; g < 2; ++g) {
                bf16x8 bf[16];
                #pragma unroll
                for (int v = 0; v < 16; ++v)
                    bf[v] = *(const bf16x8*)(zb + (v*16 + n)*64 + g*32 + 8*q);
                #pragma unroll
                for (int v = 0; v < 16; ++v) {
                    const int T = j0a + n + v;
                    const int off = (g*128 + T)*32 + ((q ^ ((T>>1)&3)) << 3);
                    const bf16x8 a = *(const bf16x8*)(rb + off);
                    acc = __builtin_amdgcn_mfma_f32_16x16x32_bf16(a, bf[v], acc, 0, 0, 0);
                }
            }
            const int ii = 15 - n;
            *(f32x4*)(part + ((size_t)(b*96 + r0 + it)*16 + ii)*112 + j0a + 4*q) = acc;
        }

        // 3) finish loads (selects) + A-compute row r0+it+1 -> rowbuf[(it+1)&1]
        if (it < 5) {
            float* Wn = W[it % 3];               // overwrite oldest (r0+it-1)
            #pragma unroll
            for (int m = 0; m < 5; ++m) {
                const bool ok = rok && !(m == 0 && ledge) && !(m == 4 && redge);
                Wn[4*m+0] = ok ? raw[m].x : 0.f;
                Wn[4*m+1] = ok ? raw[m].y : 0.f;
                Wn[4*m+2] = ok ? raw[m].z : 0.f;
                Wn[4*m+3] = ok ? raw[m].w : 0.f;
            }
            const float* fm1 = W[(it + 1) % 3];  // row r0+it
            const float* fc  = W[(it + 2) % 3];  // row r0+it+1
            const float* fp1 = Wn;               // row r0+it+2
            ushortT* rbw = &rowbuf[(it + 1) & 1][0] + g_ * 4096;
            #pragma unroll
            for (int jj = 0; jj < 12; ++jj) {
                const float a = bias
                  + fm1[jj+3]*w[0] + fm1[jj+4]*w[1] + fm1[jj+5]*w[2]
                  + fc [jj+3]*w[3] + fc [jj+4]*w[4] + fc [jj+5]*w[5] + fc[jj+4]
                  + fp1[jj+3]*w[6] + fp1[jj+4]*w[7] + fp1[jj+5]*w[8];
                const int T = j0 + jj + 8;
                rbw[T*32 + ((chunk ^ ((T>>1)&3)) << 3) + pos] = f2bf(gelu_fast(a));
            }
            __syncthreads();
        }
    }
}

// ---------------------------------------------------------------------------
// K-reduce (vectorized): out[b][i][4j4..] = OUT_SCALE * sum_r part band rows.
// Each thread: 4 consecutive j via f32x4 band loads (<=16 terms).
// ---------------------------------------------------------------------------
__global__ __launch_bounds__(256) void k_reduce(
    const float* __restrict__ part, float* __restrict__ out)
{
    const int gid = blockIdx.x * 256 + threadIdx.x;
    if (gid >= 64 * 97 * 25) return;
    const int j4 = gid % 25;
    const int t  = gid / 25;
    const int i  = t % 97;
    const int b  = t / 97;
    const int j  = j4 * 4;

    int rlo = i - 8;  if (rlo < 0)  rlo = 0;
    int rhi = i + 7;  if (rhi > 95) rhi = 95;

    // index ((b*96 + r)*16 + (i-r+7))*112 + j ; per r++ delta = 15*112 = 1680
    const float* p = part + ((size_t)(b * 96 + rlo) * 16 + (i - rlo + 7)) * 112 + j;
    f32x4 s = {0.f, 0.f, 0.f, 0.f};
    for (int r = rlo; r <= rhi; ++r) {
        s += *(const f32x4*)p;
        p += 1680;
    }
    float* ob = out + (size_t)b * 9409 + i * 97 + j;
    ob[0] = s[0] * OUT_SCALE;
    if (j < 96) {
        ob[1] = s[1] * OUT_SCALE;
        ob[2] = s[2] * OUT_SCALE;
        ob[3] = s[3] * OUT_SCALE;
    }
}

// ---------------------------------------------------------------------------
extern "C" void kernel_launch(void* const* d_in, const int* in_sizes, int n_in,
                              void* d_out, int out_size, void* d_ws, size_t ws_size,
                              hipStream_t stream)
{
    const float* z  = (const float*)d_in[0];
    const float* x  = (const float*)d_in[1];
    const float* wz = (const float*)d_in[2];
    const float* bz = (const float*)d_in[3];
    const float* wx = (const float*)d_in[4];
    const float* bx = (const float*)d_in[5];
    float* out = (float*)d_out;

    // workspace: ZB (2 MB) then part[64][96][16][112] f32 (44.04 MB)
    ushortT* zbuf = (ushortT*)d_ws;
    float*   partw = (float*)((char*)d_ws + (size_t)64 * 16384 * 2);

    k_gelu_z<<<dim3(64, 4), 256, 0, stream>>>(z, wz, bz, zbuf);
    k_fused<<<dim3(1024), 512, 0, stream>>>(x, wx, bx, zbuf, partw);
    const int nred = 64 * 97 * 25;
    k_reduce<<<dim3((nred + 255) / 256), 256, 0, stream>>>(partw, out);

    (void)in_sizes; (void)n_in; (void)ws_size; (void)out_size;
}